// Round 1
// baseline (36929.489 us; speedup 1.0000x reference)
//
#include <hip/hip_runtime.h>

// ---------------------------------------------------------------------------
// TTS forward on MI355X. Structure:
//   embed -> conv1(+BN+ReLU) -> conv2(+BN+ReLU) -> persistent biLSTM encoder
//   -> W_eff fold (decoder input GEMM folded into recurrent weights)
//   -> persistent 800-step decoder LSTM (fused mel/gate output duty)
// All matmuls via v_mfma_f32_16x16x32_f16, f32 accum/state, fp16 operands.
// ---------------------------------------------------------------------------

typedef float f4 __attribute__((ext_vector_type(4)));
typedef _Float16 h8 __attribute__((ext_vector_type(8)));
typedef _Float16 half_t;

#define B_    32
#define LTXT  256
#define TMEL  800
#define EE    512
#define HH    512
#define DD    1024
#define MM    128
#define NROWS 8192          // B_*LTXT
#define MEL_OFF  0
#define GATE_OFF 3276800    // B_*TMEL*MM
#define MASK_OFF 3302400    // + B_*TMEL

// workspace offsets (bytes, all 256-aligned)
#define WS_BAR_ENC   0ull
#define WS_BAR_DEC   128ull
#define WS_HENC      256ull          // 2*2*32*512 half = 131072
#define WS_ZERO_BYTES 131328ull      // bar + henc zeroed every call
#define WS_BUFX      131584ull       // 8192*512 half = 8 MiB   (xe / enc_in)
#define WS_BUFY      8520192ull      // 8 MiB
#define WS_CONVF     16908800ull     // 8192*512 f32 = 16 MiB
#define WS_WP1       33686016ull     // 3*512*512 half
#define WS_WP2       35258880ull
#define WS_MEAN      36831744ull     // 512 f32
#define WS_RSTD      36833792ull     // 512 f32
#define WS_WIHP      36835840ull     // 2*2048*512 half = 4 MiB
#define WS_WHHP      41030144ull     // 4 MiB
#define WS_BSUM      45224448ull     // 2*2048 f32
#define WS_WEFF      45240832ull     // 4096*1024 half = 8 MiB
#define WS_W0        53629440ull     // 8 MiB
#define WS_BEFF      62018048ull     // 4096 f32
#define WS_B0        62034432ull     // 4096 f32
#define WS_PROJW     62050816ull     // 128*1024 half
#define WS_PROJG     62312960ull     // 16*1024 half
#define WS_HD        62345728ull     // 2*32*1024 half = 131072
#define WS_CEL       62476800ull     // 32*1024 f32 = 131072

__device__ __forceinline__ float sigm(float x) { return 1.f / (1.f + __expf(-x)); }
__device__ __forceinline__ float tanh_f(float x) {
    float e = __expf(2.f * x);
    return 1.f - 2.f / (e + 1.f);   // -> +-1 at extremes, no NaN
}

// sense-free generation barrier: bar[0]=arrive, bar[1]=generation
__device__ __forceinline__ void gbar(unsigned* bar, unsigned target, unsigned nb) {
    __syncthreads();
    if (threadIdx.x == 0) {
        __threadfence();
        unsigned old = __hip_atomic_fetch_add(&bar[0], 1u, __ATOMIC_ACQ_REL, __HIP_MEMORY_SCOPE_AGENT);
        if (old == nb - 1u) {
            __hip_atomic_store(&bar[0], 0u, __ATOMIC_RELAXED, __HIP_MEMORY_SCOPE_AGENT);
            __hip_atomic_fetch_add(&bar[1], 1u, __ATOMIC_RELEASE, __HIP_MEMORY_SCOPE_AGENT);
        } else {
            while (__hip_atomic_load(&bar[1], __ATOMIC_ACQUIRE, __HIP_MEMORY_SCOPE_AGENT) < target) {
                __builtin_amdgcn_s_sleep(1);
            }
        }
    }
    __syncthreads();
}

// ---------------- small prep kernels ----------------

__global__ void k_embed(const int* __restrict__ x, const float* __restrict__ emb,
                        half_t* __restrict__ out) {
    int row = blockIdx.x;
    int tok = x[row];
    const float* e = emb + (size_t)tok * EE;
    half_t* o = out + (size_t)row * EE;
    for (int c = threadIdx.x; c < EE; c += blockDim.x) o[c] = (half_t)e[c];
}

// conv_w (E,E,3) f32 -> wp[s][eo][ei] half
__global__ void k_packconvw(const float* __restrict__ w, half_t* __restrict__ wp) {
    int idx = blockIdx.x * 256 + threadIdx.x;
    if (idx >= 3 * EE * EE) return;
    int s = idx / (EE * EE);
    int rem = idx - s * EE * EE;
    int eo = rem >> 9, ei = rem & 511;
    wp[idx] = (half_t)w[(size_t)eo * (EE * 3) + ei * 3 + s];
}

// conv as GEMM: out[row][eo] = sum_s sum_ei A[row+s-1][ei]*W[eo][ei][s] + bias
__global__ __launch_bounds__(256) void k_conv(const half_t* __restrict__ A,
                                              const half_t* __restrict__ Wp,
                                              const float* __restrict__ bias,
                                              float* __restrict__ out) {
    const int nt = blockIdx.x, et = blockIdx.y;
    const int tid = threadIdx.x;
    const int wv = tid >> 6, l = tid & 63, quad = l >> 4, lo = l & 15;
    const int rowA = nt * 64 + wv * 16 + lo;
    const int eo = et * 16 + lo;
    f4 acc = {0.f, 0.f, 0.f, 0.f};
    for (int s = 0; s < 3; ++s) {
        int lsp = (rowA & 255) + s - 1;
        bool valid = (lsp >= 0) && (lsp < 256);
        int rs = rowA + s - 1;
        rs = rs < 0 ? 0 : (rs > NROWS - 1 ? NROWS - 1 : rs);
        const half_t* ab = A + (size_t)rs * EE;
        const half_t* wb = Wp + ((size_t)s * EE + eo) * EE;
#pragma unroll 4
        for (int ks = 0; ks < 16; ++ks) {
            h8 a = {0, 0, 0, 0, 0, 0, 0, 0};
            if (valid) a = *(const h8*)(ab + ks * 32 + quad * 8);
            h8 b = *(const h8*)(wb + ks * 32 + quad * 8);
            acc = __builtin_amdgcn_mfma_f32_16x16x32_f16(a, b, acc, 0, 0, 0);
        }
    }
    const int orow = nt * 64 + wv * 16 + quad * 4;
    const float bv = bias[eo];
#pragma unroll
    for (int r = 0; r < 4; ++r) out[(size_t)(orow + r) * EE + eo] = acc[r] + bv;
}

__global__ __launch_bounds__(256) void k_bnstats(const float* __restrict__ x,
                                                 float* __restrict__ mean,
                                                 float* __restrict__ rstd) {
    const int c = blockIdx.x;
    float s = 0.f, ss = 0.f;
    for (int n = threadIdx.x; n < NROWS; n += 256) {
        float v = x[(size_t)n * EE + c];
        s += v; ss += v * v;
    }
#pragma unroll
    for (int off = 32; off > 0; off >>= 1) { s += __shfl_down(s, off); ss += __shfl_down(ss, off); }
    __shared__ float as[4], ass[4];
    int wv = threadIdx.x >> 6;
    if ((threadIdx.x & 63) == 0) { as[wv] = s; ass[wv] = ss; }
    __syncthreads();
    if (threadIdx.x == 0) {
        float S = as[0] + as[1] + as[2] + as[3];
        float SS = ass[0] + ass[1] + ass[2] + ass[3];
        float m = S / (float)NROWS;
        float var = SS / (float)NROWS - m * m;
        mean[c] = m;
        rstd[c] = rsqrtf(var + 1e-5f);
    }
}

__global__ void k_bnapply(const float* __restrict__ x, const float* __restrict__ mean,
                          const float* __restrict__ rstd, const float* __restrict__ g,
                          const float* __restrict__ beta, half_t* __restrict__ out) {
    int idx = blockIdx.x * 256 + threadIdx.x;
    if (idx >= NROWS * EE) return;
    int c = idx & (EE - 1);
    float v = (x[idx] - mean[c]) * rstd[c] * g[c] + beta[c];
    out[idx] = (half_t)(v > 0.f ? v : 0.f);
}

// (4H,H) f32 -> permuted half: p = he*4+g, row = g*Hdim+he; K = 1<<kshift
__global__ void k_packrec(const float* __restrict__ src, half_t* __restrict__ dst,
                          int Hdim, int kshift, int total) {
    int idx = blockIdx.x * 256 + threadIdx.x;
    if (idx >= total) return;
    int p = idx >> kshift;
    int k = idx & ((1 << kshift) - 1);
    int he = p >> 2, g = p & 3;
    dst[idx] = (half_t)src[((size_t)g * Hdim + he) * (size_t)(1 << kshift) + k];
}

__global__ void k_bsumenc(const float* __restrict__ bf, const float* __restrict__ bhf,
                          const float* __restrict__ bb, const float* __restrict__ bhb,
                          float* __restrict__ bsum) {
    int p = blockIdx.x * 256 + threadIdx.x;
    if (p >= 4096) return;
    int dir = p >> 11, pp = p & 2047;
    int he = pp >> 2, g = pp & 3;
    int row = g * HH + he;
    bsum[p] = dir ? (bb[row] + bhb[row]) : (bf[row] + bhf[row]);
}

// W_eff = dwhh + dwih@proj_w  (permuted, half); also permuted dwhh (for t=1)
__global__ __launch_bounds__(256) void k_weff(const float* __restrict__ dwhh,
                                              const float* __restrict__ dwih,
                                              const float* __restrict__ projw,
                                              half_t* __restrict__ weff,
                                              half_t* __restrict__ w0) {
    int row = blockIdx.x;                       // 0..4095
    int k = blockIdx.y * 256 + threadIdx.x;     // 0..1023
    float v = dwhh[(size_t)row * DD + k];
    float acc = v;
    for (int m = 0; m < MM; ++m) acc += dwih[(size_t)row * MM + m] * projw[(size_t)m * DD + k];
    int p = ((row & (DD - 1)) << 2) | (row >> 10);
    weff[(size_t)p * DD + k] = (half_t)acc;
    w0[(size_t)p * DD + k] = (half_t)v;
}

__global__ void k_bdec(const float* __restrict__ dbih, const float* __restrict__ dbhh,
                       const float* __restrict__ dwih, const float* __restrict__ projb,
                       float* __restrict__ beff, float* __restrict__ b0) {
    int p = blockIdx.x * 256 + threadIdx.x;
    if (p >= 4096) return;
    int he = p >> 2, g = p & 3;
    int row = g * DD + he;
    float bb = dbih[row] + dbhh[row];
    float acc = bb;
    for (int m = 0; m < MM; ++m) acc += dwih[(size_t)row * MM + m] * projb[m];
    b0[p] = bb;
    beff[p] = acc;
}

__global__ void k_cast(const float* __restrict__ src, half_t* __restrict__ dst, int n) {
    int idx = blockIdx.x * 256 + threadIdx.x;
    if (idx < n) dst[idx] = (half_t)src[idx];
}

__global__ void k_projg(const float* __restrict__ gw, half_t* __restrict__ pg) {
    int idx = blockIdx.x * 256 + threadIdx.x;
    if (idx >= 16 * DD) return;
    int row = idx >> 10, k = idx & (DD - 1);
    pg[idx] = (half_t)(row == 0 ? gw[k] : 0.f);
}

__global__ void k_mask(const int* __restrict__ lens, float* __restrict__ out) {
    int idx = blockIdx.x * 256 + threadIdx.x;
    if (idx >= B_ * TMEL) return;
    int b = idx / TMEL, t = idx - b * TMEL;
    out[MASK_OFF + idx] = (t > lens[b]) ? 1.f : 0.f;
}

// ---------------- persistent bidirectional encoder LSTM ----------------
// 256 blocks x 128 thr. block j: dir=j>>7, owns h-elems [4*(j&127), +4).
// Per step: gates(32b x 16rows) = x_t@wih.T + h@whh.T + bias via MFMA,
// LSTM update with packed-seq freeze (t < len), h exchanged via global dbuf.
__global__ __launch_bounds__(128) void k_enc(const half_t* __restrict__ X,
                                             const half_t* __restrict__ wihp,
                                             const half_t* __restrict__ whhp,
                                             const float* __restrict__ bsum,
                                             const int* __restrict__ lens,
                                             half_t* __restrict__ henc,   // [2][2][32][512]
                                             half_t* __restrict__ hd0,    // [32][1024]
                                             float* __restrict__ cel,     // [32][1024]
                                             unsigned* __restrict__ bar) {
    const int j = blockIdx.x;
    const int dir = j >> 7;
    const int sub = j & 127;
    const int tid = threadIdx.x;
    const int wv = tid >> 6, l = tid & 63, quad = l >> 4, lo = l & 15;
    const int bfr = wv * 16 + lo;      // batch for A-frag
    const int ue = tid >> 5, ub = tid & 31;  // update mapping: elem, batch

    __shared__ float s_g[32][17];
    __shared__ float s_c[4][32];
    __shared__ float s_h[4][32];
    __shared__ int s_len[32];

    if (tid < 32) s_len[tid] = lens[tid];
    s_c[ue][ub] = 0.f;
    s_h[ue][ub] = 0.f;

    const half_t* wih_b = wihp + ((size_t)dir * 2048 + sub * 16 + lo) * 512;
    const half_t* whh_b = whhp + ((size_t)dir * 2048 + sub * 16 + lo) * 512;
    const float bias_n = bsum[dir * 2048 + sub * 16 + lo];
    __syncthreads();

    for (int t = 0; t < 256; ++t) {
        const int lb = s_len[bfr];
        int tt;
        if (dir == 0) tt = t;
        else { tt = lb - 1 - t; tt = tt < 0 ? 0 : tt; }  // clip; frozen anyway when t>=len
        const half_t* xr = X + ((size_t)bfr * 256 + tt) * 512;
        const half_t* hr = henc + (((size_t)(t & 1) * 2 + dir) * 32 + bfr) * 512;
        f4 acc = {0.f, 0.f, 0.f, 0.f};
#pragma unroll 4
        for (int ks = 0; ks < 16; ++ks) {
            h8 a = *(const h8*)(xr + ks * 32 + quad * 8);
            h8 b = *(const h8*)(wih_b + ks * 32 + quad * 8);
            acc = __builtin_amdgcn_mfma_f32_16x16x32_f16(a, b, acc, 0, 0, 0);
        }
#pragma unroll 4
        for (int ks = 0; ks < 16; ++ks) {
            h8 a = *(const h8*)(hr + ks * 32 + quad * 8);
            h8 b = *(const h8*)(whh_b + ks * 32 + quad * 8);
            acc = __builtin_amdgcn_mfma_f32_16x16x32_f16(a, b, acc, 0, 0, 0);
        }
        const int bm = wv * 16 + quad * 4;
#pragma unroll
        for (int r = 0; r < 4; ++r) s_g[bm + r][lo] = acc[r] + bias_n;
        __syncthreads();
        {
            float gi = s_g[ub][ue * 4 + 0], gf = s_g[ub][ue * 4 + 1];
            float gg = s_g[ub][ue * 4 + 2], go = s_g[ub][ue * 4 + 3];
            float iv = sigm(gi), fv = sigm(gf), gv = tanh_f(gg), ov = sigm(go);
            float cn = fv * s_c[ue][ub] + iv * gv;
            float hn = ov * tanh_f(cn);
            if (t < s_len[ub]) { s_c[ue][ub] = cn; s_h[ue][ub] = hn; }
            henc[(((size_t)((t & 1) ^ 1) * 2 + dir) * 32 + ub) * 512 + sub * 4 + ue] =
                (half_t)s_h[ue][ub];
        }
        if (t < 255) gbar(bar, (unsigned)(t + 1), 256u);
    }
    // final states -> decoder init (hid, cel)
    hd0[(size_t)ub * 1024 + dir * 512 + sub * 4 + ue] = (half_t)s_h[ue][ub];
    cel[(size_t)ub * 1024 + dir * 512 + sub * 4 + ue] = s_c[ue][ub];
}

// ---------------- persistent decoder LSTM ----------------
// 256 blocks x 128 thr, block j owns h-elems [4j,4j+4). gates = hd@W_eff.T+b_eff
// (t==1: dwhh,b0). Blocks 0..7: mel output duty (fused 2nd MFMA); block 8: gate.
__global__ __launch_bounds__(128) void k_dec(const half_t* __restrict__ Weff,
                                             const half_t* __restrict__ W0,
                                             const float* __restrict__ beff,
                                             const float* __restrict__ b0,
                                             const half_t* __restrict__ projwb,
                                             const half_t* __restrict__ projg,
                                             const float* __restrict__ projb,
                                             const float* __restrict__ gateb,
                                             const int* __restrict__ mlens,
                                             const float* __restrict__ cel,
                                             half_t* __restrict__ hd,   // [2][32][1024]
                                             float* __restrict__ out,
                                             unsigned* __restrict__ bar) {
    const int j = blockIdx.x;
    const int tid = threadIdx.x;
    const int wv = tid >> 6, l = tid & 63, quad = l >> 4, lo = l & 15;
    const int bfr = wv * 16 + lo;
    const int ue = tid >> 5, ub = tid & 31;
    const int he0 = j * 4;

    __shared__ float s_g[32][17];
    __shared__ float s_c[4][32];
    __shared__ int s_len[32];

    if (tid < 32) s_len[tid] = mlens[tid];
    s_c[ue][ub] = cel[(size_t)ub * 1024 + he0 + ue];
    const float biasE = beff[j * 16 + lo];
    const float bias0 = b0[j * 16 + lo];
    const bool meld = (j < 8);
    const bool gated = (j == 8);
    const half_t* pw = meld ? (projwb + (size_t)(j * 16 + lo) * 1024)
                            : (gated ? (projg + (size_t)lo * 1024) : (const half_t*)nullptr);
    const float biasP = meld ? projb[j * 16 + lo] : 0.f;
    const half_t* wb_eff = Weff + ((size_t)j * 16 + lo) * 1024;
    const half_t* wb_0 = W0 + ((size_t)j * 16 + lo) * 1024;
    __syncthreads();

    for (int t = 1; t <= TMEL; ++t) {
        const half_t* hr = hd + (size_t)((t - 1) & 1) * (32 * 1024) + (size_t)bfr * 1024;
        const half_t* wb = (t == 1) ? wb_0 : wb_eff;
        f4 acc = {0.f, 0.f, 0.f, 0.f};
        if ((meld || gated) && t >= 2) {
            f4 accm = {0.f, 0.f, 0.f, 0.f};
#pragma unroll 4
            for (int ks = 0; ks < 32; ++ks) {
                h8 a = *(const h8*)(hr + ks * 32 + quad * 8);
                h8 b = *(const h8*)(wb + ks * 32 + quad * 8);
                acc = __builtin_amdgcn_mfma_f32_16x16x32_f16(a, b, acc, 0, 0, 0);
                h8 p = *(const h8*)(pw + ks * 32 + quad * 8);
                accm = __builtin_amdgcn_mfma_f32_16x16x32_f16(a, p, accm, 0, 0, 0);
            }
            const int pos = t - 2;  // output for iteration t-1 (0-indexed)
            if (meld) {
#pragma unroll
                for (int r = 0; r < 4; ++r) {
                    int b = wv * 16 + quad * 4 + r;
                    float v = accm[r] + biasP;
                    if (pos > s_len[b]) v = 0.f;
                    out[(size_t)b * (TMEL * MM) + (size_t)pos * MM + j * 16 + lo] = v;
                }
            } else if (lo == 0) {
#pragma unroll
                for (int r = 0; r < 4; ++r) {
                    int b = wv * 16 + quad * 4 + r;
                    float v = accm[r] + gateb[0];
                    if (pos > s_len[b]) v = 1000.f;
                    out[GATE_OFF + (size_t)b * TMEL + pos] = v;
                }
            }
        } else {
#pragma unroll 4
            for (int ks = 0; ks < 32; ++ks) {
                h8 a = *(const h8*)(hr + ks * 32 + quad * 8);
                h8 b = *(const h8*)(wb + ks * 32 + quad * 8);
                acc = __builtin_amdgcn_mfma_f32_16x16x32_f16(a, b, acc, 0, 0, 0);
            }
        }
        const float bn = (t == 1) ? bias0 : biasE;
        const int bm = wv * 16 + quad * 4;
#pragma unroll
        for (int r = 0; r < 4; ++r) s_g[bm + r][lo] = acc[r] + bn;
        __syncthreads();
        {
            float gi = s_g[ub][ue * 4 + 0], gf = s_g[ub][ue * 4 + 1];
            float gg = s_g[ub][ue * 4 + 2], go = s_g[ub][ue * 4 + 3];
            float iv = sigm(gi), fv = sigm(gf), gv = tanh_f(gg), ov = sigm(go);
            float cn = fv * s_c[ue][ub] + iv * gv;
            s_c[ue][ub] = cn;
            float hn = ov * tanh_f(cn);
            hd[((size_t)(t & 1) * 32 + ub) * 1024 + he0 + ue] = (half_t)hn;
        }
        gbar(bar, (unsigned)t, 256u);
    }
    // epilogue: outputs for pos 799 from hd_800 (buf 0)
    if (meld || gated) {
        const half_t* hr = hd + (size_t)bfr * 1024;
        f4 accm = {0.f, 0.f, 0.f, 0.f};
#pragma unroll 4
        for (int ks = 0; ks < 32; ++ks) {
            h8 a = *(const h8*)(hr + ks * 32 + quad * 8);
            h8 p = *(const h8*)(pw + ks * 32 + quad * 8);
            accm = __builtin_amdgcn_mfma_f32_16x16x32_f16(a, p, accm, 0, 0, 0);
        }
        if (meld) {
#pragma unroll
            for (int r = 0; r < 4; ++r) {
                int b = wv * 16 + quad * 4 + r;
                float v = accm[r] + biasP;
                if (799 > s_len[b]) v = 0.f;
                out[(size_t)b * (TMEL * MM) + (size_t)799 * MM + j * 16 + lo] = v;
            }
        } else if (lo == 0) {
#pragma unroll
            for (int r = 0; r < 4; ++r) {
                int b = wv * 16 + quad * 4 + r;
                float v = accm[r] + gateb[0];
                if (799 > s_len[b]) v = 1000.f;
                out[GATE_OFF + (size_t)b * TMEL + 799] = v;
            }
        }
    }
}

// ---------------------------------------------------------------------------

extern "C" void kernel_launch(void* const* d_in, const int* in_sizes, int n_in,
                              void* d_out, int out_size, void* d_ws, size_t ws_size,
                              hipStream_t stream) {
    const int* x = (const int*)d_in[0];
    const int* tlens = (const int*)d_in[1];
    // d_in[2] = y (values unused, only shape)
    const int* mlens = (const int*)d_in[3];
    const float* emb = (const float*)d_in[4];
    const float* c1w = (const float*)d_in[5];
    const float* c1b = (const float*)d_in[6];
    const float* bn1g = (const float*)d_in[7];
    const float* bn1b = (const float*)d_in[8];
    const float* c2w = (const float*)d_in[9];
    const float* c2b = (const float*)d_in[10];
    const float* bn2g = (const float*)d_in[11];
    const float* bn2b = (const float*)d_in[12];
    const float* wihf = (const float*)d_in[13];
    const float* whhf = (const float*)d_in[14];
    const float* bihf = (const float*)d_in[15];
    const float* bhhf = (const float*)d_in[16];
    const float* wihb = (const float*)d_in[17];
    const float* whhb = (const float*)d_in[18];
    const float* bihb = (const float*)d_in[19];
    const float* bhhb = (const float*)d_in[20];
    const float* dwih = (const float*)d_in[21];
    const float* dwhh = (const float*)d_in[22];
    const float* dbih = (const float*)d_in[23];
    const float* dbhh = (const float*)d_in[24];
    const float* projw = (const float*)d_in[25];
    const float* projb = (const float*)d_in[26];
    const float* gatew = (const float*)d_in[27];
    const float* gateb = (const float*)d_in[28];
    float* out = (float*)d_out;
    char* ws = (char*)d_ws;

    unsigned* bar_enc = (unsigned*)(ws + WS_BAR_ENC);
    unsigned* bar_dec = (unsigned*)(ws + WS_BAR_DEC);
    half_t* henc = (half_t*)(ws + WS_HENC);
    half_t* bufX = (half_t*)(ws + WS_BUFX);
    half_t* bufY = (half_t*)(ws + WS_BUFY);
    float* convf = (float*)(ws + WS_CONVF);
    half_t* wp1 = (half_t*)(ws + WS_WP1);
    half_t* wp2 = (half_t*)(ws + WS_WP2);
    float* meanb = (float*)(ws + WS_MEAN);
    float* rstdb = (float*)(ws + WS_RSTD);
    half_t* wihp = (half_t*)(ws + WS_WIHP);
    half_t* whhp = (half_t*)(ws + WS_WHHP);
    float* bsum = (float*)(ws + WS_BSUM);
    half_t* weff = (half_t*)(ws + WS_WEFF);
    half_t* w0 = (half_t*)(ws + WS_W0);
    float* beff = (float*)(ws + WS_BEFF);
    float* b0 = (float*)(ws + WS_B0);
    half_t* projwb = (half_t*)(ws + WS_PROJW);
    half_t* projg = (half_t*)(ws + WS_PROJG);
    half_t* hd = (half_t*)(ws + WS_HD);
    float* cel = (float*)(ws + WS_CEL);

    // zero barrier state + encoder h double-buffer
    hipMemsetAsync(d_ws, 0, (size_t)WS_ZERO_BYTES, stream);

    // front-end
    k_embed<<<NROWS, 256, 0, stream>>>(x, emb, bufX);
    k_packconvw<<<(3 * EE * EE + 255) / 256, 256, 0, stream>>>(c1w, wp1);
    k_conv<<<dim3(128, 32), 256, 0, stream>>>(bufX, wp1, c1b, convf);
    k_bnstats<<<EE, 256, 0, stream>>>(convf, meanb, rstdb);
    k_bnapply<<<(NROWS * EE) / 256, 256, 0, stream>>>(convf, meanb, rstdb, bn1g, bn1b, bufY);
    k_packconvw<<<(3 * EE * EE + 255) / 256, 256, 0, stream>>>(c2w, wp2);
    k_conv<<<dim3(128, 32), 256, 0, stream>>>(bufY, wp2, c2b, convf);
    k_bnstats<<<EE, 256, 0, stream>>>(convf, meanb, rstdb);
    k_bnapply<<<(NROWS * EE) / 256, 256, 0, stream>>>(convf, meanb, rstdb, bn2g, bn2b, bufX);

    // encoder weight prep (permuted half)
    const int encTot = 2048 * 512;
    k_packrec<<<(encTot + 255) / 256, 256, 0, stream>>>(wihf, wihp, HH, 9, encTot);
    k_packrec<<<(encTot + 255) / 256, 256, 0, stream>>>(wihb, wihp + encTot, HH, 9, encTot);
    k_packrec<<<(encTot + 255) / 256, 256, 0, stream>>>(whhf, whhp, HH, 9, encTot);
    k_packrec<<<(encTot + 255) / 256, 256, 0, stream>>>(whhb, whhp + encTot, HH, 9, encTot);
    k_bsumenc<<<16, 256, 0, stream>>>(bihf, bhhf, bihb, bhhb, bsum);

    // persistent bidirectional encoder
    k_enc<<<256, 128, 0, stream>>>(bufX, wihp, whhp, bsum, tlens, henc, hd, cel, bar_enc);

    // decoder weight prep (W_eff fold) — overlaps nothing (stream), cheap
    k_weff<<<dim3(4096, 4), 256, 0, stream>>>(dwhh, dwih, projw, weff, w0);
    k_bdec<<<16, 256, 0, stream>>>(dbih, dbhh, dwih, projb, beff, b0);
    k_cast<<<(MM * DD + 255) / 256, 256, 0, stream>>>(projw, projwb, MM * DD);
    k_projg<<<(16 * DD + 255) / 256, 256, 0, stream>>>(gatew, projg);

    // persistent decoder (writes mel + gate outputs, masked)
    k_dec<<<256, 128, 0, stream>>>(weff, w0, beff, b0, projwb, projg, projb, gateb,
                                   mlens, cel, hd, out, bar_dec);

    // mask output
    k_mask<<<(B_ * TMEL + 255) / 256, 256, 0, stream>>>(mlens, out);

    (void)in_sizes; (void)n_in; (void)out_size; (void)ws_size;
}

// Round 2
// 26754.901 us; speedup vs baseline: 1.3803x; 1.3803x over previous
//
#include <hip/hip_runtime.h>

// ---------------------------------------------------------------------------
// TTS forward on MI355X.
//   embed -> conv1(+BN+ReLU) -> conv2(+BN+ReLU) -> persistent biLSTM encoder
//   -> W_eff fold (decoder input GEMM folded into recurrent weights)
//   -> persistent 800-step decoder LSTM (fused mel/gate output duty)
// Round 2: relaxed sc1 (agent-scope atomic) h-exchange + tree barrier, no
// acquire/release cache maintenance in the recurrence loops; 64x512 blocks.
// ---------------------------------------------------------------------------

typedef float f4 __attribute__((ext_vector_type(4)));
typedef _Float16 h8 __attribute__((ext_vector_type(8)));
typedef _Float16 half_t;
typedef unsigned long long u64;

#define B_    32
#define LTXT  256
#define TMEL  800
#define EE    512
#define HH    512
#define DD    1024
#define MM    128
#define NROWS 8192          // B_*LTXT
#define GATE_OFF 3276800    // B_*TMEL*MM
#define MASK_OFF 3302400    // + B_*TMEL

// workspace offsets (bytes)
#define WS_BARS      0ull            // 3 domains x 2048 B (encF, encB, dec)
#define WS_HENC      6144ull         // 2*2*32*512 half = 131072
#define WS_ZERO_BYTES 137216ull      // bars + henc zeroed every call
#define WS_BUFX      137216ull       // 8192*512 half = 8 MiB
#define WS_BUFY      8525824ull      // 8 MiB
#define WS_CONVF     16914432ull     // 8192*512 f32 = 16 MiB (reused by WEFF/W0)
#define WS_WEFF      16914432ull     // 4096*1024 half = 8 MiB   (after convs done)
#define WS_W0        25303040ull     // 8 MiB
#define WS_WP1       33691648ull     // 3*512*512 half
#define WS_WP2       35264512ull
#define WS_MEAN      36837376ull     // 512 f32
#define WS_RSTD      36839424ull     // 512 f32
#define WS_WIHP      36841472ull     // 2*2048*512 half = 4 MiB
#define WS_WHHP      41035776ull     // 4 MiB
#define WS_BSUM      45230080ull     // 4096 f32
#define WS_BEFF      45246464ull     // 4096 f32
#define WS_B0        45262848ull     // 4096 f32
#define WS_PROJW     45279232ull     // 128*1024 half
#define WS_PROJG     45541376ull     // 16*1024 half
#define WS_HD        45574144ull     // 2*32*1024 half = 131072
#define WS_CEL       45705216ull     // 32*1024 f32 = 131072
// total 45836288

__device__ __forceinline__ float sigm(float x) { return 1.f / (1.f + __expf(-x)); }
__device__ __forceinline__ float tanh_f(float x) {
    float e = __expf(2.f * x);
    return 1.f - 2.f / (e + 1.f);
}

// relaxed agent-scope (sc1, L3-coherent) data movement — no cache maintenance
__device__ __forceinline__ h8 ld_h8a(const half_t* p) {
    const u64* q = (const u64*)p;
    union { u64 u[2]; h8 v; } x;
    x.u[0] = __hip_atomic_load(q + 0, __ATOMIC_RELAXED, __HIP_MEMORY_SCOPE_AGENT);
    x.u[1] = __hip_atomic_load(q + 1, __ATOMIC_RELAXED, __HIP_MEMORY_SCOPE_AGENT);
    return x.v;
}
__device__ __forceinline__ void st_h4a(half_t* p, half_t a, half_t b, half_t c, half_t d) {
    union { half_t h[4]; u64 u; } x;
    x.h[0] = a; x.h[1] = b; x.h[2] = c; x.h[3] = d;
    __hip_atomic_store((u64*)p, x.u, __ATOMIC_RELAXED, __HIP_MEMORY_SCOPE_AGENT);
}

// Two-level tree barrier, accumulating counters (no reset, no wraparound).
// bar[0]=root, bar[16]=generation, bar[32+g*32]=group g counter.
// All relaxed: HW ordering comes from the s_waitcnt(0)+__syncthreads drain
// (each wave drains its sc1 stores before arriving) and sc1 ops serializing
// at the L3 coherence point. Spin polls are relaxed sc1 loads: always fresh,
// and NO buffer_inv / wbl2 is ever emitted in the hot loop.
__device__ __forceinline__ void gbar(unsigned* bar, unsigned g, unsigned target,
                                     unsigned gs_mul, unsigned ng_mul) {
    __builtin_amdgcn_s_waitcnt(0);
    __syncthreads();
    if (threadIdx.x == 0) {
        __atomic_signal_fence(__ATOMIC_SEQ_CST);
        unsigned old = __hip_atomic_fetch_add(bar + 32 + (size_t)g * 32, 1u,
                                              __ATOMIC_RELAXED, __HIP_MEMORY_SCOPE_AGENT);
        if (old == target * gs_mul - 1u) {
            unsigned ro = __hip_atomic_fetch_add(bar, 1u,
                                                 __ATOMIC_RELAXED, __HIP_MEMORY_SCOPE_AGENT);
            if (ro == target * ng_mul - 1u)
                __hip_atomic_store(bar + 16, target, __ATOMIC_RELAXED,
                                   __HIP_MEMORY_SCOPE_AGENT);
        }
        while (__hip_atomic_load(bar + 16, __ATOMIC_RELAXED,
                                 __HIP_MEMORY_SCOPE_AGENT) < target)
            __builtin_amdgcn_s_sleep(1);
        __atomic_signal_fence(__ATOMIC_SEQ_CST);
    }
    __syncthreads();
}

// ---------------- small prep kernels ----------------

__global__ void k_embed(const int* __restrict__ x, const float* __restrict__ emb,
                        half_t* __restrict__ out) {
    int row = blockIdx.x;
    int tok = x[row];
    const float* e = emb + (size_t)tok * EE;
    half_t* o = out + (size_t)row * EE;
    for (int c = threadIdx.x; c < EE; c += blockDim.x) o[c] = (half_t)e[c];
}

__global__ void k_packconvw(const float* __restrict__ w, half_t* __restrict__ wp) {
    int idx = blockIdx.x * 256 + threadIdx.x;
    if (idx >= 3 * EE * EE) return;
    int s = idx / (EE * EE);
    int rem = idx - s * EE * EE;
    int eo = rem >> 9, ei = rem & 511;
    wp[idx] = (half_t)w[(size_t)eo * (EE * 3) + ei * 3 + s];
}

__global__ __launch_bounds__(256) void k_conv(const half_t* __restrict__ A,
                                              const half_t* __restrict__ Wp,
                                              const float* __restrict__ bias,
                                              float* __restrict__ out) {
    const int nt = blockIdx.x, et = blockIdx.y;
    const int tid = threadIdx.x;
    const int wv = tid >> 6, l = tid & 63, quad = l >> 4, lo = l & 15;
    const int rowA = nt * 64 + wv * 16 + lo;
    const int eo = et * 16 + lo;
    f4 acc = {0.f, 0.f, 0.f, 0.f};
    for (int s = 0; s < 3; ++s) {
        int lsp = (rowA & 255) + s - 1;
        bool valid = (lsp >= 0) && (lsp < 256);
        int rs = rowA + s - 1;
        rs = rs < 0 ? 0 : (rs > NROWS - 1 ? NROWS - 1 : rs);
        const half_t* ab = A + (size_t)rs * EE;
        const half_t* wb = Wp + ((size_t)s * EE + eo) * EE;
#pragma unroll 4
        for (int ks = 0; ks < 16; ++ks) {
            h8 a = {0, 0, 0, 0, 0, 0, 0, 0};
            if (valid) a = *(const h8*)(ab + ks * 32 + quad * 8);
            h8 b = *(const h8*)(wb + ks * 32 + quad * 8);
            acc = __builtin_amdgcn_mfma_f32_16x16x32_f16(a, b, acc, 0, 0, 0);
        }
    }
    const int orow = nt * 64 + wv * 16 + quad * 4;
    const float bv = bias[eo];
#pragma unroll
    for (int r = 0; r < 4; ++r) out[(size_t)(orow + r) * EE + eo] = acc[r] + bv;
}

__global__ __launch_bounds__(256) void k_bnstats(const float* __restrict__ x,
                                                 float* __restrict__ mean,
                                                 float* __restrict__ rstd) {
    const int c = blockIdx.x;
    float s = 0.f, ss = 0.f;
    for (int n = threadIdx.x; n < NROWS; n += 256) {
        float v = x[(size_t)n * EE + c];
        s += v; ss += v * v;
    }
#pragma unroll
    for (int off = 32; off > 0; off >>= 1) { s += __shfl_down(s, off); ss += __shfl_down(ss, off); }
    __shared__ float as[4], ass[4];
    int wv = threadIdx.x >> 6;
    if ((threadIdx.x & 63) == 0) { as[wv] = s; ass[wv] = ss; }
    __syncthreads();
    if (threadIdx.x == 0) {
        float S = as[0] + as[1] + as[2] + as[3];
        float SS = ass[0] + ass[1] + ass[2] + ass[3];
        float m = S / (float)NROWS;
        float var = SS / (float)NROWS - m * m;
        mean[c] = m;
        rstd[c] = rsqrtf(var + 1e-5f);
    }
}

__global__ void k_bnapply(const float* __restrict__ x, const float* __restrict__ mean,
                          const float* __restrict__ rstd, const float* __restrict__ g,
                          const float* __restrict__ beta, half_t* __restrict__ out) {
    int idx = blockIdx.x * 256 + threadIdx.x;
    if (idx >= NROWS * EE) return;
    int c = idx & (EE - 1);
    float v = (x[idx] - mean[c]) * rstd[c] * g[c] + beta[c];
    out[idx] = (half_t)(v > 0.f ? v : 0.f);
}

__global__ void k_packrec(const float* __restrict__ src, half_t* __restrict__ dst,
                          int Hdim, int kshift, int total) {
    int idx = blockIdx.x * 256 + threadIdx.x;
    if (idx >= total) return;
    int p = idx >> kshift;
    int k = idx & ((1 << kshift) - 1);
    int he = p >> 2, g = p & 3;
    dst[idx] = (half_t)src[((size_t)g * Hdim + he) * (size_t)(1 << kshift) + k];
}

__global__ void k_bsumenc(const float* __restrict__ bf, const float* __restrict__ bhf,
                          const float* __restrict__ bb, const float* __restrict__ bhb,
                          float* __restrict__ bsum) {
    int p = blockIdx.x * 256 + threadIdx.x;
    if (p >= 4096) return;
    int dir = p >> 11, pp = p & 2047;
    int he = pp >> 2, g = pp & 3;
    int row = g * HH + he;
    bsum[p] = dir ? (bb[row] + bhb[row]) : (bf[row] + bhf[row]);
}

__global__ __launch_bounds__(256) void k_weff(const float* __restrict__ dwhh,
                                              const float* __restrict__ dwih,
                                              const float* __restrict__ projw,
                                              half_t* __restrict__ weff,
                                              half_t* __restrict__ w0) {
    int row = blockIdx.x;
    int k = blockIdx.y * 256 + threadIdx.x;
    float v = dwhh[(size_t)row * DD + k];
    float acc = v;
    for (int m = 0; m < MM; ++m) acc += dwih[(size_t)row * MM + m] * projw[(size_t)m * DD + k];
    int p = ((row & (DD - 1)) << 2) | (row >> 10);
    weff[(size_t)p * DD + k] = (half_t)acc;
    w0[(size_t)p * DD + k] = (half_t)v;
}

__global__ void k_bdec(const float* __restrict__ dbih, const float* __restrict__ dbhh,
                       const float* __restrict__ dwih, const float* __restrict__ projb,
                       float* __restrict__ beff, float* __restrict__ b0) {
    int p = blockIdx.x * 256 + threadIdx.x;
    if (p >= 4096) return;
    int he = p >> 2, g = p & 3;
    int row = g * DD + he;
    float bb = dbih[row] + dbhh[row];
    float acc = bb;
    for (int m = 0; m < MM; ++m) acc += dwih[(size_t)row * MM + m] * projb[m];
    b0[p] = bb;
    beff[p] = acc;
}

__global__ void k_cast(const float* __restrict__ src, half_t* __restrict__ dst, int n) {
    int idx = blockIdx.x * 256 + threadIdx.x;
    if (idx < n) dst[idx] = (half_t)src[idx];
}

__global__ void k_projg(const float* __restrict__ gw, half_t* __restrict__ pg) {
    int idx = blockIdx.x * 256 + threadIdx.x;
    if (idx >= 16 * DD) return;
    int row = idx >> 10, k = idx & (DD - 1);
    pg[idx] = (half_t)(row == 0 ? gw[k] : 0.f);
}

__global__ void k_mask(const int* __restrict__ lens, float* __restrict__ out) {
    int idx = blockIdx.x * 256 + threadIdx.x;
    if (idx >= B_ * TMEL) return;
    int b = idx / TMEL, t = idx - b * TMEL;
    out[MASK_OFF + idx] = (t > lens[b]) ? 1.f : 0.f;
}

// ---------------- persistent bidirectional encoder LSTM ----------------
// 64 blocks x 512 thr. dir = j>>5 (independent barrier domains), sub = j&31
// owns 16 h-elems. 8 waves: rg=wv>>1 (4 row-groups of 16 gate rows), bh=wv&1
// (batch half). h exchanged via sc1 atomics; barrier 4 groups x 8.
__global__ __launch_bounds__(512) void k_enc(const half_t* __restrict__ X,
                                             const half_t* __restrict__ wihp,
                                             const half_t* __restrict__ whhp,
                                             const float* __restrict__ bsum,
                                             const int* __restrict__ lens,
                                             half_t* __restrict__ henc,   // [2][2][32][512]
                                             half_t* __restrict__ hd0,    // [32][1024]
                                             float* __restrict__ cel,     // [32][1024]
                                             unsigned* __restrict__ bars) {
    const int j = blockIdx.x;
    const int dir = j >> 5, sub = j & 31;
    const int tid = threadIdx.x;
    const int wv = tid >> 6, l = tid & 63, quad = l >> 4, lo = l & 15;
    const int rg = wv >> 1, bh = wv & 1;
    const int bfr = bh * 16 + lo;
    const int ue = tid >> 5, ub = tid & 31;
    unsigned* bar = bars + (size_t)dir * 512;

    __shared__ float s_g[32][65];
    __shared__ float s_c[16][32];
    __shared__ float s_h[16][32];
    __shared__ half_t s_hh[16][32];
    __shared__ int s_len[32];

    if (tid < 32) s_len[tid] = lens[tid];
    s_c[ue][ub] = 0.f;
    s_h[ue][ub] = 0.f;

    const int pr = dir * 2048 + sub * 64 + rg * 16 + lo;
    const half_t* wih_b = wihp + (size_t)pr * 512;
    const half_t* whh_b = whhp + (size_t)pr * 512;
    const float bias_n = bsum[pr];
    __syncthreads();

    for (int t = 0; t < 256; ++t) {
        const int lb = s_len[bfr];
        int tt = (dir == 0) ? t : (lb - 1 - t);
        tt = tt < 0 ? 0 : tt;
        const half_t* xr = X + ((size_t)bfr * 256 + tt) * 512;
        const half_t* hr = henc + (((size_t)(t & 1) * 2 + dir) * 32 + bfr) * 512;
        f4 acc = {0.f, 0.f, 0.f, 0.f};
#pragma unroll 4
        for (int ks = 0; ks < 16; ++ks) {
            h8 a = *(const h8*)(xr + ks * 32 + quad * 8);
            h8 b = *(const h8*)(wih_b + ks * 32 + quad * 8);
            acc = __builtin_amdgcn_mfma_f32_16x16x32_f16(a, b, acc, 0, 0, 0);
        }
#pragma unroll 4
        for (int ks = 0; ks < 16; ++ks) {
            h8 a = ld_h8a(hr + ks * 32 + quad * 8);
            h8 b = *(const h8*)(whh_b + ks * 32 + quad * 8);
            acc = __builtin_amdgcn_mfma_f32_16x16x32_f16(a, b, acc, 0, 0, 0);
        }
        const int bm = bh * 16 + quad * 4, cm = rg * 16 + lo;
#pragma unroll
        for (int r = 0; r < 4; ++r) s_g[bm + r][cm] = acc[r] + bias_n;
        __syncthreads();
        {
            float gi = s_g[ub][ue * 4 + 0], gf = s_g[ub][ue * 4 + 1];
            float gg = s_g[ub][ue * 4 + 2], go = s_g[ub][ue * 4 + 3];
            float cn = sigm(gf) * s_c[ue][ub] + sigm(gi) * tanh_f(gg);
            float hn = sigm(go) * tanh_f(cn);
            if (t < s_len[ub]) { s_c[ue][ub] = cn; s_h[ue][ub] = hn; }
            s_hh[ue][ub] = (half_t)s_h[ue][ub];
        }
        __syncthreads();
        if (tid < 128) {
            int eq = tid >> 5, b2 = tid & 31;
            half_t* dst = henc + (((size_t)((t & 1) ^ 1) * 2 + dir) * 32 + b2) * 512
                          + sub * 16 + eq * 4;
            st_h4a(dst, s_hh[eq * 4 + 0][b2], s_hh[eq * 4 + 1][b2],
                   s_hh[eq * 4 + 2][b2], s_hh[eq * 4 + 3][b2]);
        }
        if (t < 255) gbar(bar, (unsigned)(sub & 3), (unsigned)(t + 1), 8u, 4u);
    }
    hd0[(size_t)ub * 1024 + dir * 512 + sub * 16 + ue] = (half_t)s_h[ue][ub];
    cel[(size_t)ub * 1024 + dir * 512 + sub * 16 + ue] = s_c[ue][ub];
}

// ---------------- persistent decoder LSTM ----------------
// 64 blocks x 512 thr, block j owns h-elems [16j,16j+16) (gate rows 64j..64j+64).
// Blocks 0..7 waves rg==0: fused mel output; block 8 rg==0: gate output.
__global__ __launch_bounds__(512) void k_dec(const half_t* __restrict__ Weff,
                                             const half_t* __restrict__ W0,
                                             const float* __restrict__ beff,
                                             const float* __restrict__ b0,
                                             const half_t* __restrict__ projwb,
                                             const half_t* __restrict__ projg,
                                             const float* __restrict__ projb,
                                             const float* __restrict__ gateb,
                                             const int* __restrict__ mlens,
                                             const float* __restrict__ cel,
                                             half_t* __restrict__ hd,   // [2][32][1024]
                                             float* __restrict__ out,
                                             unsigned* __restrict__ bar) {
    const int j = blockIdx.x;
    const int tid = threadIdx.x;
    const int wv = tid >> 6, l = tid & 63, quad = l >> 4, lo = l & 15;
    const int rg = wv >> 1, bh = wv & 1;
    const int bfr = bh * 16 + lo;
    const int ue = tid >> 5, ub = tid & 31;

    __shared__ float s_g[32][65];
    __shared__ float s_c[16][32];
    __shared__ half_t s_hh[16][32];
    __shared__ int s_len[32];

    if (tid < 32) s_len[tid] = mlens[tid];
    s_c[ue][ub] = cel[(size_t)ub * 1024 + j * 16 + ue];
    const int pr = j * 64 + rg * 16 + lo;
    const float biasE = beff[pr], bias0 = b0[pr];
    const bool meld = (j < 8), gated = (j == 8);
    const bool duty = (meld || gated) && (rg == 0);
    const half_t* pw = nullptr;
    float biasP = 0.f;
    if (duty) {
        pw = meld ? (projwb + (size_t)(j * 16 + lo) * 1024) : (projg + (size_t)lo * 1024);
        biasP = meld ? projb[j * 16 + lo] : gateb[0];
    }
    const half_t* wbE = Weff + (size_t)pr * 1024;
    const half_t* wb0 = W0 + (size_t)pr * 1024;
    __syncthreads();

    for (int t = 1; t <= TMEL; ++t) {
        const half_t* hr = hd + (size_t)((t - 1) & 1) * 32768 + (size_t)bfr * 1024;
        const half_t* wb = (t == 1) ? wb0 : wbE;
        f4 acc = {0.f, 0.f, 0.f, 0.f};
        if (duty && t >= 2) {
            f4 accm = {0.f, 0.f, 0.f, 0.f};
#pragma unroll 4
            for (int ks = 0; ks < 32; ++ks) {
                h8 a = ld_h8a(hr + ks * 32 + quad * 8);
                h8 b = *(const h8*)(wb + ks * 32 + quad * 8);
                acc = __builtin_amdgcn_mfma_f32_16x16x32_f16(a, b, acc, 0, 0, 0);
                h8 p = *(const h8*)(pw + ks * 32 + quad * 8);
                accm = __builtin_amdgcn_mfma_f32_16x16x32_f16(a, p, accm, 0, 0, 0);
            }
            const int pos = t - 2;
            if (meld) {
#pragma unroll
                for (int r = 0; r < 4; ++r) {
                    int b = bh * 16 + quad * 4 + r;
                    float v = accm[r] + biasP;
                    if (pos > s_len[b]) v = 0.f;
                    __builtin_nontemporal_store(v,
                        &out[(size_t)b * (TMEL * MM) + (size_t)pos * MM + j * 16 + lo]);
                }
            } else if (lo == 0) {
#pragma unroll
                for (int r = 0; r < 4; ++r) {
                    int b = bh * 16 + quad * 4 + r;
                    float v = accm[r] + biasP;
                    if (pos > s_len[b]) v = 1000.f;
                    __builtin_nontemporal_store(v, &out[GATE_OFF + (size_t)b * TMEL + pos]);
                }
            }
        } else {
#pragma unroll 8
            for (int ks = 0; ks < 32; ++ks) {
                h8 a = ld_h8a(hr + ks * 32 + quad * 8);
                h8 b = *(const h8*)(wb + ks * 32 + quad * 8);
                acc = __builtin_amdgcn_mfma_f32_16x16x32_f16(a, b, acc, 0, 0, 0);
            }
        }
        const float bn = (t == 1) ? bias0 : biasE;
        const int bm = bh * 16 + quad * 4, cm = rg * 16 + lo;
#pragma unroll
        for (int r = 0; r < 4; ++r) s_g[bm + r][cm] = acc[r] + bn;
        __syncthreads();
        {
            float gi = s_g[ub][ue * 4 + 0], gf = s_g[ub][ue * 4 + 1];
            float gg = s_g[ub][ue * 4 + 2], go = s_g[ub][ue * 4 + 3];
            float cn = sigm(gf) * s_c[ue][ub] + sigm(gi) * tanh_f(gg);
            s_c[ue][ub] = cn;
            s_hh[ue][ub] = (half_t)(sigm(go) * tanh_f(cn));
        }
        __syncthreads();
        if (tid < 128) {
            int eq = tid >> 5, b2 = tid & 31;
            half_t* dst = hd + (size_t)(t & 1) * 32768 + (size_t)b2 * 1024 + j * 16 + eq * 4;
            st_h4a(dst, s_hh[eq * 4 + 0][b2], s_hh[eq * 4 + 1][b2],
                   s_hh[eq * 4 + 2][b2], s_hh[eq * 4 + 3][b2]);
        }
        gbar(bar, (unsigned)(j & 7), (unsigned)t, 8u, 8u);
    }
    // epilogue: outputs for pos 799 from hd_800 (buffer 0)
    if (duty) {
        const half_t* hr = hd + (size_t)bfr * 1024;
        f4 accm = {0.f, 0.f, 0.f, 0.f};
#pragma unroll 4
        for (int ks = 0; ks < 32; ++ks) {
            h8 a = ld_h8a(hr + ks * 32 + quad * 8);
            h8 p = *(const h8*)(pw + ks * 32 + quad * 8);
            accm = __builtin_amdgcn_mfma_f32_16x16x32_f16(a, p, accm, 0, 0, 0);
        }
        if (meld) {
#pragma unroll
            for (int r = 0; r < 4; ++r) {
                int b = bh * 16 + quad * 4 + r;
                float v = accm[r] + biasP;
                if (799 > s_len[b]) v = 0.f;
                out[(size_t)b * (TMEL * MM) + (size_t)799 * MM + j * 16 + lo] = v;
            }
        } else if (lo == 0) {
#pragma unroll
            for (int r = 0; r < 4; ++r) {
                int b = bh * 16 + quad * 4 + r;
                float v = accm[r] + biasP;
                if (799 > s_len[b]) v = 1000.f;
                out[GATE_OFF + (size_t)b * TMEL + 799] = v;
            }
        }
    }
}

// ---------------------------------------------------------------------------

extern "C" void kernel_launch(void* const* d_in, const int* in_sizes, int n_in,
                              void* d_out, int out_size, void* d_ws, size_t ws_size,
                              hipStream_t stream) {
    const int* x = (const int*)d_in[0];
    const int* tlens = (const int*)d_in[1];
    const int* mlens = (const int*)d_in[3];
    const float* emb = (const float*)d_in[4];
    const float* c1w = (const float*)d_in[5];
    const float* c1b = (const float*)d_in[6];
    const float* bn1g = (const float*)d_in[7];
    const float* bn1b = (const float*)d_in[8];
    const float* c2w = (const float*)d_in[9];
    const float* c2b = (const float*)d_in[10];
    const float* bn2g = (const float*)d_in[11];
    const float* bn2b = (const float*)d_in[12];
    const float* wihf = (const float*)d_in[13];
    const float* whhf = (const float*)d_in[14];
    const float* bihf = (const float*)d_in[15];
    const float* bhhf = (const float*)d_in[16];
    const float* wihb = (const float*)d_in[17];
    const float* whhb = (const float*)d_in[18];
    const float* bihb = (const float*)d_in[19];
    const float* bhhb = (const float*)d_in[20];
    const float* dwih = (const float*)d_in[21];
    const float* dwhh = (const float*)d_in[22];
    const float* dbih = (const float*)d_in[23];
    const float* dbhh = (const float*)d_in[24];
    const float* projw = (const float*)d_in[25];
    const float* projb = (const float*)d_in[26];
    const float* gatew = (const float*)d_in[27];
    const float* gateb = (const float*)d_in[28];
    float* out = (float*)d_out;
    char* ws = (char*)d_ws;

    unsigned* bars = (unsigned*)(ws + WS_BARS);          // encF @0, encB @2048, dec @4096
    unsigned* bar_dec = (unsigned*)(ws + WS_BARS + 4096);
    half_t* henc = (half_t*)(ws + WS_HENC);
    half_t* bufX = (half_t*)(ws + WS_BUFX);
    half_t* bufY = (half_t*)(ws + WS_BUFY);
    float* convf = (float*)(ws + WS_CONVF);
    half_t* weff = (half_t*)(ws + WS_WEFF);
    half_t* w0 = (half_t*)(ws + WS_W0);
    half_t* wp1 = (half_t*)(ws + WS_WP1);
    half_t* wp2 = (half_t*)(ws + WS_WP2);
    float* meanb = (float*)(ws + WS_MEAN);
    float* rstdb = (float*)(ws + WS_RSTD);
    half_t* wihp = (half_t*)(ws + WS_WIHP);
    half_t* whhp = (half_t*)(ws + WS_WHHP);
    float* bsum = (float*)(ws + WS_BSUM);
    float* beff = (float*)(ws + WS_BEFF);
    float* b0 = (float*)(ws + WS_B0);
    half_t* projwb = (half_t*)(ws + WS_PROJW);
    half_t* projg = (half_t*)(ws + WS_PROJG);
    half_t* hd = (half_t*)(ws + WS_HD);
    float* cel = (float*)(ws + WS_CEL);

    // zero barrier state + encoder h double-buffer
    hipMemsetAsync(d_ws, 0, (size_t)WS_ZERO_BYTES, stream);

    // front-end
    k_embed<<<NROWS, 256, 0, stream>>>(x, emb, bufX);
    k_packconvw<<<(3 * EE * EE + 255) / 256, 256, 0, stream>>>(c1w, wp1);
    k_conv<<<dim3(128, 32), 256, 0, stream>>>(bufX, wp1, c1b, convf);
    k_bnstats<<<EE, 256, 0, stream>>>(convf, meanb, rstdb);
    k_bnapply<<<(NROWS * EE) / 256, 256, 0, stream>>>(convf, meanb, rstdb, bn1g, bn1b, bufY);
    k_packconvw<<<(3 * EE * EE + 255) / 256, 256, 0, stream>>>(c2w, wp2);
    k_conv<<<dim3(128, 32), 256, 0, stream>>>(bufY, wp2, c2b, convf);
    k_bnstats<<<EE, 256, 0, stream>>>(convf, meanb, rstdb);
    k_bnapply<<<(NROWS * EE) / 256, 256, 0, stream>>>(convf, meanb, rstdb, bn2g, bn2b, bufX);

    // encoder weight prep
    const int encTot = 2048 * 512;
    k_packrec<<<(encTot + 255) / 256, 256, 0, stream>>>(wihf, wihp, HH, 9, encTot);
    k_packrec<<<(encTot + 255) / 256, 256, 0, stream>>>(wihb, wihp + encTot, HH, 9, encTot);
    k_packrec<<<(encTot + 255) / 256, 256, 0, stream>>>(whhf, whhp, HH, 9, encTot);
    k_packrec<<<(encTot + 255) / 256, 256, 0, stream>>>(whhb, whhp + encTot, HH, 9, encTot);
    k_bsumenc<<<16, 256, 0, stream>>>(bihf, bhhf, bihb, bhhb, bsum);

    // persistent bidirectional encoder
    k_enc<<<64, 512, 0, stream>>>(bufX, wihp, whhp, bsum, tlens, henc, hd, cel, bars);

    // decoder weight prep (W_eff fold) — writes into retired convf region
    k_weff<<<dim3(4096, 4), 256, 0, stream>>>(dwhh, dwih, projw, weff, w0);
    k_bdec<<<16, 256, 0, stream>>>(dbih, dbhh, dwih, projb, beff, b0);
    k_cast<<<(MM * DD + 255) / 256, 256, 0, stream>>>(projw, projwb, MM * DD);
    k_projg<<<(16 * DD + 255) / 256, 256, 0, stream>>>(gatew, projg);

    // persistent decoder
    k_dec<<<64, 512, 0, stream>>>(weff, w0, beff, b0, projwb, projg, projb, gateb,
                                  mlens, cel, hd, out, bar_dec);

    // mask output
    k_mask<<<(B_ * TMEL + 255) / 256, 256, 0, stream>>>(mlens, out);

    (void)in_sizes; (void)n_in; (void)out_size; (void)ws_size;
}

// Round 3
// 14761.359 us; speedup vs baseline: 2.5018x; 1.8125x over previous
//
#include <hip/hip_runtime.h>

// ---------------------------------------------------------------------------
// TTS forward on MI355X.
//   embed -> conv1(+BN+ReLU) -> conv2(+BN+ReLU) -> persistent biLSTM encoder
//   -> W_eff fold (decoder input GEMM folded into recurrent weights)
//   -> persistent 800-step decoder LSTM (fused mel/gate output duty)
// Round 3: h-state exchanged via rotating never-reused ring buffers (fresh
// plain cached loads, no atomics / no cache maintenance), producers write
// through to L3 with asm sc0 sc1 stores, LDS-staged h slot per block.
// ---------------------------------------------------------------------------

typedef float f4 __attribute__((ext_vector_type(4)));
typedef _Float16 h8 __attribute__((ext_vector_type(8)));
typedef _Float16 half_t;
typedef unsigned long long u64;

#define B_    32
#define LTXT  256
#define TMEL  800
#define EE    512
#define HH    512
#define DD    1024
#define MM    128
#define NROWS 8192          // B_*LTXT
#define GATE_OFF 3276800    // B_*TMEL*MM
#define MASK_OFF 3302400    // + B_*TMEL

#define RING_D 801          // decoder h ring slots (never reused in 800 steps)
#define RING_E 257          // encoder h ring slots
#define HOP    13           // slot hop stride (coprime with both rings)

// workspace offsets (bytes)
#define WS_BARS      0ull              // 3 domains x 8192 B, padded lines
#define WS_HENC      32768ull          // RING_E * 65536
#define WS_ZERO_BYTES 98304ull         // bars + henc slot 0
#define WS_HD        16875520ull       // RING_D * 65536
#define WS_BUFX      69369856ull       // 8 MiB
#define WS_BUFY      77758464ull       // 8 MiB
#define WS_CONVF     86147072ull       // 16 MiB (reused by WEFF/W0 after convs)
#define WS_WEFF      86147072ull
#define WS_W0        94535680ull
#define WS_WP1       102924288ull
#define WS_WP2       104497152ull
#define WS_WIHP      106070016ull      // 4 MiB
#define WS_WHHP      110264320ull      // 4 MiB
#define WS_BSUM      114458624ull
#define WS_BEFF      114475008ull
#define WS_B0        114491392ull
#define WS_MEAN      114507776ull
#define WS_RSTD      114509824ull
#define WS_PROJW     114511872ull
#define WS_PROJG     114774016ull
#define WS_CEL       114806784ull
// total ~114.9 MB

__device__ __forceinline__ float sigm(float x) { return 1.f / (1.f + __expf(-x)); }
__device__ __forceinline__ float tanh_f(float x) {
    float e = __expf(2.f * x);
    return 1.f - 2.f / (e + 1.f);
}

// write-through store (bypass L1/L2, land at L3 coherence point), non-atomic
__device__ __forceinline__ void st_wt64(void* p, u64 v) {
    asm volatile("global_store_dwordx2 %0, %1, off sc0 sc1" :: "v"(p), "v"(v) : "memory");
}

// Two-level tree barrier, accumulating counters, padded cache lines.
// dwords: root @0, gen @256, group g @512+g*64. All relaxed agent-scope;
// ordering from s_waitcnt(0)+__syncthreads drain before arrive.
__device__ __forceinline__ void gbar(unsigned* bar, unsigned g, unsigned target,
                                     unsigned gs_mul, unsigned ng_mul) {
    __builtin_amdgcn_s_waitcnt(0);
    __syncthreads();
    if (threadIdx.x == 0) {
        __atomic_signal_fence(__ATOMIC_SEQ_CST);
        unsigned old = __hip_atomic_fetch_add(bar + 512 + (size_t)g * 64, 1u,
                                              __ATOMIC_RELAXED, __HIP_MEMORY_SCOPE_AGENT);
        if (old == target * gs_mul - 1u) {
            unsigned ro = __hip_atomic_fetch_add(bar, 1u,
                                                 __ATOMIC_RELAXED, __HIP_MEMORY_SCOPE_AGENT);
            if (ro == target * ng_mul - 1u)
                __hip_atomic_store(bar + 256, target, __ATOMIC_RELAXED,
                                   __HIP_MEMORY_SCOPE_AGENT);
        }
        while (__hip_atomic_load(bar + 256, __ATOMIC_RELAXED,
                                 __HIP_MEMORY_SCOPE_AGENT) < target)
            __builtin_amdgcn_s_sleep(1);
        __atomic_signal_fence(__ATOMIC_SEQ_CST);
    }
    __syncthreads();
}

// ---------------- small prep kernels ----------------

__global__ void k_embed(const int* __restrict__ x, const float* __restrict__ emb,
                        half_t* __restrict__ out) {
    int row = blockIdx.x;
    int tok = x[row];
    const float* e = emb + (size_t)tok * EE;
    half_t* o = out + (size_t)row * EE;
    for (int c = threadIdx.x; c < EE; c += blockDim.x) o[c] = (half_t)e[c];
}

__global__ void k_packconvw(const float* __restrict__ w, half_t* __restrict__ wp) {
    int idx = blockIdx.x * 256 + threadIdx.x;
    if (idx >= 3 * EE * EE) return;
    int s = idx / (EE * EE);
    int rem = idx - s * EE * EE;
    int eo = rem >> 9, ei = rem & 511;
    wp[idx] = (half_t)w[(size_t)eo * (EE * 3) + ei * 3 + s];
}

__global__ __launch_bounds__(256) void k_conv(const half_t* __restrict__ A,
                                              const half_t* __restrict__ Wp,
                                              const float* __restrict__ bias,
                                              float* __restrict__ out) {
    const int nt = blockIdx.x, et = blockIdx.y;
    const int tid = threadIdx.x;
    const int wv = tid >> 6, l = tid & 63, quad = l >> 4, lo = l & 15;
    const int rowA = nt * 64 + wv * 16 + lo;
    const int eo = et * 16 + lo;
    f4 acc = {0.f, 0.f, 0.f, 0.f};
    for (int s = 0; s < 3; ++s) {
        int lsp = (rowA & 255) + s - 1;
        bool valid = (lsp >= 0) && (lsp < 256);
        int rs = rowA + s - 1;
        rs = rs < 0 ? 0 : (rs > NROWS - 1 ? NROWS - 1 : rs);
        const half_t* ab = A + (size_t)rs * EE;
        const half_t* wb = Wp + ((size_t)s * EE + eo) * EE;
#pragma unroll 4
        for (int ks = 0; ks < 16; ++ks) {
            h8 a = {0, 0, 0, 0, 0, 0, 0, 0};
            if (valid) a = *(const h8*)(ab + ks * 32 + quad * 8);
            h8 b = *(const h8*)(wb + ks * 32 + quad * 8);
            acc = __builtin_amdgcn_mfma_f32_16x16x32_f16(a, b, acc, 0, 0, 0);
        }
    }
    const int orow = nt * 64 + wv * 16 + quad * 4;
    const float bv = bias[eo];
#pragma unroll
    for (int r = 0; r < 4; ++r) out[(size_t)(orow + r) * EE + eo] = acc[r] + bv;
}

__global__ __launch_bounds__(256) void k_bnstats(const float* __restrict__ x,
                                                 float* __restrict__ mean,
                                                 float* __restrict__ rstd) {
    const int c = blockIdx.x;
    float s = 0.f, ss = 0.f;
    for (int n = threadIdx.x; n < NROWS; n += 256) {
        float v = x[(size_t)n * EE + c];
        s += v; ss += v * v;
    }
#pragma unroll
    for (int off = 32; off > 0; off >>= 1) { s += __shfl_down(s, off); ss += __shfl_down(ss, off); }
    __shared__ float as[4], ass[4];
    int wv = threadIdx.x >> 6;
    if ((threadIdx.x & 63) == 0) { as[wv] = s; ass[wv] = ss; }
    __syncthreads();
    if (threadIdx.x == 0) {
        float S = as[0] + as[1] + as[2] + as[3];
        float SS = ass[0] + ass[1] + ass[2] + ass[3];
        float m = S / (float)NROWS;
        float var = SS / (float)NROWS - m * m;
        mean[c] = m;
        rstd[c] = rsqrtf(var + 1e-5f);
    }
}

__global__ void k_bnapply(const float* __restrict__ x, const float* __restrict__ mean,
                          const float* __restrict__ rstd, const float* __restrict__ g,
                          const float* __restrict__ beta, half_t* __restrict__ out) {
    int idx = blockIdx.x * 256 + threadIdx.x;
    if (idx >= NROWS * EE) return;
    int c = idx & (EE - 1);
    float v = (x[idx] - mean[c]) * rstd[c] * g[c] + beta[c];
    out[idx] = (half_t)(v > 0.f ? v : 0.f);
}

__global__ void k_packrec(const float* __restrict__ src, half_t* __restrict__ dst,
                          int Hdim, int kshift, int total) {
    int idx = blockIdx.x * 256 + threadIdx.x;
    if (idx >= total) return;
    int p = idx >> kshift;
    int k = idx & ((1 << kshift) - 1);
    int he = p >> 2, g = p & 3;
    dst[idx] = (half_t)src[((size_t)g * Hdim + he) * (size_t)(1 << kshift) + k];
}

__global__ void k_bsumenc(const float* __restrict__ bf, const float* __restrict__ bhf,
                          const float* __restrict__ bb, const float* __restrict__ bhb,
                          float* __restrict__ bsum) {
    int p = blockIdx.x * 256 + threadIdx.x;
    if (p >= 4096) return;
    int dir = p >> 11, pp = p & 2047;
    int he = pp >> 2, g = pp & 3;
    int row = g * HH + he;
    bsum[p] = dir ? (bb[row] + bhb[row]) : (bf[row] + bhf[row]);
}

__global__ __launch_bounds__(256) void k_weff(const float* __restrict__ dwhh,
                                              const float* __restrict__ dwih,
                                              const float* __restrict__ projw,
                                              half_t* __restrict__ weff,
                                              half_t* __restrict__ w0) {
    int row = blockIdx.x;
    int k = blockIdx.y * 256 + threadIdx.x;
    float v = dwhh[(size_t)row * DD + k];
    float acc = v;
    for (int m = 0; m < MM; ++m) acc += dwih[(size_t)row * MM + m] * projw[(size_t)m * DD + k];
    int p = ((row & (DD - 1)) << 2) | (row >> 10);
    weff[(size_t)p * DD + k] = (half_t)acc;
    w0[(size_t)p * DD + k] = (half_t)v;
}

__global__ void k_bdec(const float* __restrict__ dbih, const float* __restrict__ dbhh,
                       const float* __restrict__ dwih, const float* __restrict__ projb,
                       float* __restrict__ beff, float* __restrict__ b0) {
    int p = blockIdx.x * 256 + threadIdx.x;
    if (p >= 4096) return;
    int he = p >> 2, g = p & 3;
    int row = g * DD + he;
    float bb = dbih[row] + dbhh[row];
    float acc = bb;
    for (int m = 0; m < MM; ++m) acc += dwih[(size_t)row * MM + m] * projb[m];
    b0[p] = bb;
    beff[p] = acc;
}

__global__ void k_cast(const float* __restrict__ src, half_t* __restrict__ dst, int n) {
    int idx = blockIdx.x * 256 + threadIdx.x;
    if (idx < n) dst[idx] = (half_t)src[idx];
}

__global__ void k_projg(const float* __restrict__ gw, half_t* __restrict__ pg) {
    int idx = blockIdx.x * 256 + threadIdx.x;
    if (idx >= 16 * DD) return;
    int row = idx >> 10, k = idx & (DD - 1);
    pg[idx] = (half_t)(row == 0 ? gw[k] : 0.f);
}

__global__ void k_mask(const int* __restrict__ lens, float* __restrict__ out) {
    int idx = blockIdx.x * 256 + threadIdx.x;
    if (idx >= B_ * TMEL) return;
    int b = idx / TMEL, t = idx - b * TMEL;
    out[MASK_OFF + idx] = (t > lens[b]) ? 1.f : 0.f;
}

// ---------------- persistent bidirectional encoder LSTM ----------------
// 64 blocks x 512 thr. dir=j>>5 (independent barrier domains), sub=j&31 owns
// 16 h-elems. h ring: slot t read, slot t+1 written (never-reused addresses).
// LDS stride 520 halfs (260 words %32==4 -> 2-way free b128).
__global__ __launch_bounds__(512) void k_enc(const half_t* __restrict__ X,
                                             const half_t* __restrict__ wihp,
                                             const half_t* __restrict__ whhp,
                                             const float* __restrict__ bsum,
                                             const int* __restrict__ lens,
                                             half_t* __restrict__ henc,   // ring [RING_E][2][32][512]
                                             half_t* __restrict__ hd0,    // ring slot 0: [32][1024]
                                             float* __restrict__ cel,     // [32][1024]
                                             unsigned* __restrict__ bars) {
    const int j = blockIdx.x;
    const int dir = j >> 5, sub = j & 31;
    const int tid = threadIdx.x;
    const int wv = tid >> 6, l = tid & 63, quad = l >> 4, lo = l & 15;
    const int rg = wv >> 1, bh = wv & 1;
    const int bfr = bh * 16 + lo;
    const int ue = tid >> 5, ub = tid & 31;
    unsigned* bar = bars + (size_t)dir * 2048;

    __shared__ half_t s_hd[32 * 520];
    __shared__ float s_g[32][65];
    __shared__ float s_c[16][32];
    __shared__ float s_h[16][32];
    __shared__ half_t s_hh[16][32];
    __shared__ int s_len[32];

    if (tid < 32) s_len[tid] = lens[tid];
    s_c[ue][ub] = 0.f;
    s_h[ue][ub] = 0.f;

    const int pr = dir * 2048 + sub * 64 + rg * 16 + lo;
    const half_t* wih_b = wihp + (size_t)pr * 512;
    const half_t* whh_b = whhp + (size_t)pr * 512;
    const float bias_n = bsum[pr];

    int sp = 0, sn = HOP;
    __syncthreads();

    for (int t = 0; t < 256; ++t) {
        // issue h-slot coop loads (fresh cold addresses -> L3)
        const half_t* src = henc + (size_t)sp * 32768 + (size_t)dir * 16384;
        h8 tmp0 = *(const h8*)(src + (size_t)(tid + 0 * 512) * 8);
        h8 tmp1 = *(const h8*)(src + (size_t)(tid + 1 * 512) * 8);
        h8 tmp2 = *(const h8*)(src + (size_t)(tid + 2 * 512) * 8);
        h8 tmp3 = *(const h8*)(src + (size_t)(tid + 3 * 512) * 8);

        // x-part MFMA overlaps the h loads
        const int lb = s_len[bfr];
        int tt = (dir == 0) ? t : (lb - 1 - t);
        tt = tt < 0 ? 0 : tt;
        const half_t* xr = X + ((size_t)bfr * 256 + tt) * 512;
        f4 accA = {0.f, 0.f, 0.f, 0.f}, accB = {0.f, 0.f, 0.f, 0.f};
#pragma unroll 4
        for (int ks = 0; ks < 16; ++ks) {
            h8 a = *(const h8*)(xr + ks * 32 + quad * 8);
            h8 b = *(const h8*)(wih_b + ks * 32 + quad * 8);
            accA = __builtin_amdgcn_mfma_f32_16x16x32_f16(a, b, accA, 0, 0, 0);
        }

        // stage h into LDS
        {
            int c0 = tid;
            *(h8*)(s_hd + (size_t)(c0 >> 6) * 520 + (c0 & 63) * 8) = tmp0;
            int c1 = tid + 512;
            *(h8*)(s_hd + (size_t)(c1 >> 6) * 520 + (c1 & 63) * 8) = tmp1;
            int c2 = tid + 1024;
            *(h8*)(s_hd + (size_t)(c2 >> 6) * 520 + (c2 & 63) * 8) = tmp2;
            int c3 = tid + 1536;
            *(h8*)(s_hd + (size_t)(c3 >> 6) * 520 + (c3 & 63) * 8) = tmp3;
        }
        __syncthreads();

#pragma unroll 4
        for (int ks = 0; ks < 16; ++ks) {
            h8 a = *(const h8*)(s_hd + (size_t)bfr * 520 + ks * 32 + quad * 8);
            h8 b = *(const h8*)(whh_b + ks * 32 + quad * 8);
            accB = __builtin_amdgcn_mfma_f32_16x16x32_f16(a, b, accB, 0, 0, 0);
        }
        const int bm = bh * 16 + quad * 4, cm = rg * 16 + lo;
#pragma unroll
        for (int r = 0; r < 4; ++r) s_g[bm + r][cm] = accA[r] + accB[r] + bias_n;
        __syncthreads();
        {
            float gi = s_g[ub][ue * 4 + 0], gf = s_g[ub][ue * 4 + 1];
            float gg = s_g[ub][ue * 4 + 2], go = s_g[ub][ue * 4 + 3];
            float cn = sigm(gf) * s_c[ue][ub] + sigm(gi) * tanh_f(gg);
            float hn = sigm(go) * tanh_f(cn);
            if (t < s_len[ub]) { s_c[ue][ub] = cn; s_h[ue][ub] = hn; }
            s_hh[ue][ub] = (half_t)s_h[ue][ub];
        }
        __syncthreads();
        if (tid < 128 && t < 255) {
            int eq = tid >> 5, b2 = tid & 31;
            union { half_t h[4]; u64 u; } pk;
            pk.h[0] = s_hh[eq * 4 + 0][b2]; pk.h[1] = s_hh[eq * 4 + 1][b2];
            pk.h[2] = s_hh[eq * 4 + 2][b2]; pk.h[3] = s_hh[eq * 4 + 3][b2];
            st_wt64(henc + (size_t)sn * 32768 + (size_t)dir * 16384
                    + (size_t)b2 * 512 + sub * 16 + eq * 4, pk.u);
        }
        if (t < 255) {
            gbar(bar, (unsigned)(sub & 3), (unsigned)(t + 1), 8u, 4u);
            sp = sn; sn += HOP; if (sn >= RING_E) sn -= RING_E;
        }
    }
    hd0[(size_t)ub * 1024 + dir * 512 + sub * 16 + ue] = (half_t)s_h[ue][ub];
    cel[(size_t)ub * 1024 + dir * 512 + sub * 16 + ue] = s_c[ue][ub];
}

// ---------------- persistent decoder LSTM ----------------
// 64 blocks x 512 thr, block j owns h-elems [16j,16j+16). h ring slots hop by
// HOP mod RING_D; slot 0 = encoder final hid. LDS stride 1032 halfs
// (516 words %32==4 -> 2-way free b128).
__global__ __launch_bounds__(512) void k_dec(const half_t* __restrict__ Weff,
                                             const half_t* __restrict__ W0,
                                             const float* __restrict__ beff,
                                             const float* __restrict__ b0,
                                             const half_t* __restrict__ projwb,
                                             const half_t* __restrict__ projg,
                                             const float* __restrict__ projb,
                                             const float* __restrict__ gateb,
                                             const int* __restrict__ mlens,
                                             const float* __restrict__ cel,
                                             half_t* __restrict__ hd,   // ring [RING_D][32][1024]
                                             float* __restrict__ out,
                                             unsigned* __restrict__ bar) {
    const int j = blockIdx.x;
    const int tid = threadIdx.x;
    const int wv = tid >> 6, l = tid & 63, quad = l >> 4, lo = l & 15;
    const int rg = wv >> 1, bh = wv & 1;
    const int bfr = bh * 16 + lo;
    const int ue = tid >> 5, ub = tid & 31;

    __shared__ half_t s_hd[32 * 1032];
    __shared__ float s_g[32][65];
    __shared__ float s_c[16][32];
    __shared__ half_t s_hh[16][32];
    __shared__ int s_len[32];

    if (tid < 32) s_len[tid] = mlens[tid];
    s_c[ue][ub] = cel[(size_t)ub * 1024 + j * 16 + ue];
    const int pr = j * 64 + rg * 16 + lo;
    const float biasE = beff[pr], bias0 = b0[pr];
    const bool meld = (j < 8), gated = (j == 8);
    const bool duty = (meld || gated) && (rg == 0);
    const half_t* pw = nullptr;
    float biasP = 0.f;
    if (duty) {
        pw = meld ? (projwb + (size_t)(j * 16 + lo) * 1024) : (projg + (size_t)lo * 1024);
        biasP = meld ? projb[j * 16 + lo] : gateb[0];
    }
    const half_t* wbE = Weff + (size_t)pr * 1024;
    const half_t* wb0 = W0 + (size_t)pr * 1024;

    int sp = 0, sn = HOP;
    __syncthreads();

    for (int t = 1; t <= TMEL; ++t) {
        // cooperative load of h slot (fresh cold addresses)
        const half_t* src = hd + (size_t)sp * 32768;
        {
            h8 tp[8];
#pragma unroll
            for (int i = 0; i < 8; ++i)
                tp[i] = *(const h8*)(src + (size_t)(tid + i * 512) * 8);
#pragma unroll
            for (int i = 0; i < 8; ++i) {
                int c = tid + i * 512;
                *(h8*)(s_hd + (size_t)(c >> 7) * 1032 + (c & 127) * 8) = tp[i];
            }
        }
        __syncthreads();

        const half_t* wb = (t == 1) ? wb0 : wbE;
        const half_t* ar = s_hd + (size_t)bfr * 1032 + quad * 8;
        f4 acc = {0.f, 0.f, 0.f, 0.f}, acc2 = {0.f, 0.f, 0.f, 0.f};
        if (duty && t >= 2) {
            f4 accm = {0.f, 0.f, 0.f, 0.f}, accm2 = {0.f, 0.f, 0.f, 0.f};
#pragma unroll 8
            for (int ks = 0; ks < 32; ks += 2) {
                h8 a0 = *(const h8*)(ar + ks * 32);
                h8 a1 = *(const h8*)(ar + ks * 32 + 32);
                acc = __builtin_amdgcn_mfma_f32_16x16x32_f16(a0, *(const h8*)(wb + ks * 32 + quad * 8), acc, 0, 0, 0);
                acc2 = __builtin_amdgcn_mfma_f32_16x16x32_f16(a1, *(const h8*)(wb + ks * 32 + 32 + quad * 8), acc2, 0, 0, 0);
                accm = __builtin_amdgcn_mfma_f32_16x16x32_f16(a0, *(const h8*)(pw + ks * 32 + quad * 8), accm, 0, 0, 0);
                accm2 = __builtin_amdgcn_mfma_f32_16x16x32_f16(a1, *(const h8*)(pw + ks * 32 + 32 + quad * 8), accm2, 0, 0, 0);
            }
            accm[0] += accm2[0]; accm[1] += accm2[1]; accm[2] += accm2[2]; accm[3] += accm2[3];
            const int pos = t - 2;
            if (meld) {
#pragma unroll
                for (int r = 0; r < 4; ++r) {
                    int b = bh * 16 + quad * 4 + r;
                    float v = accm[r] + biasP;
                    if (pos > s_len[b]) v = 0.f;
                    __builtin_nontemporal_store(v,
                        &out[(size_t)b * (TMEL * MM) + (size_t)pos * MM + j * 16 + lo]);
                }
            } else if (lo == 0) {
#pragma unroll
                for (int r = 0; r < 4; ++r) {
                    int b = bh * 16 + quad * 4 + r;
                    float v = accm[r] + biasP;
                    if (pos > s_len[b]) v = 1000.f;
                    __builtin_nontemporal_store(v, &out[GATE_OFF + (size_t)b * TMEL + pos]);
                }
            }
        } else {
#pragma unroll 8
            for (int ks = 0; ks < 32; ks += 2) {
                h8 a0 = *(const h8*)(ar + ks * 32);
                h8 a1 = *(const h8*)(ar + ks * 32 + 32);
                acc = __builtin_amdgcn_mfma_f32_16x16x32_f16(a0, *(const h8*)(wb + ks * 32 + quad * 8), acc, 0, 0, 0);
                acc2 = __builtin_amdgcn_mfma_f32_16x16x32_f16(a1, *(const h8*)(wb + ks * 32 + 32 + quad * 8), acc2, 0, 0, 0);
            }
        }
        const float bn = (t == 1) ? bias0 : biasE;
        const int bm = bh * 16 + quad * 4, cm = rg * 16 + lo;
#pragma unroll
        for (int r = 0; r < 4; ++r) s_g[bm + r][cm] = acc[r] + acc2[r] + bn;
        __syncthreads();
        {
            float gi = s_g[ub][ue * 4 + 0], gf = s_g[ub][ue * 4 + 1];
            float gg = s_g[ub][ue * 4 + 2], go = s_g[ub][ue * 4 + 3];
            float cn = sigm(gf) * s_c[ue][ub] + sigm(gi) * tanh_f(gg);
            s_c[ue][ub] = cn;
            s_hh[ue][ub] = (half_t)(sigm(go) * tanh_f(cn));
        }
        __syncthreads();
        if (tid < 128) {
            int eq = tid >> 5, b2 = tid & 31;
            union { half_t h[4]; u64 u; } pk;
            pk.h[0] = s_hh[eq * 4 + 0][b2]; pk.h[1] = s_hh[eq * 4 + 1][b2];
            pk.h[2] = s_hh[eq * 4 + 2][b2]; pk.h[3] = s_hh[eq * 4 + 3][b2];
            st_wt64(hd + (size_t)sn * 32768 + (size_t)b2 * 1024 + j * 16 + eq * 4, pk.u);
        }
        gbar(bar, (unsigned)(j & 7), (unsigned)t, 8u, 8u);
        sp = sn; sn += HOP; if (sn >= RING_D) sn -= RING_D;
    }
    // epilogue: outputs for pos 799 from h_800 (slot sp)
    if (meld || gated) {
        const half_t* src = hd + (size_t)sp * 32768;
        {
            h8 tp[8];
#pragma unroll
            for (int i = 0; i < 8; ++i)
                tp[i] = *(const h8*)(src + (size_t)(tid + i * 512) * 8);
#pragma unroll
            for (int i = 0; i < 8; ++i) {
                int c = tid + i * 512;
                *(h8*)(s_hd + (size_t)(c >> 7) * 1032 + (c & 127) * 8) = tp[i];
            }
        }
        __syncthreads();
        if (duty) {
            const half_t* ar = s_hd + (size_t)bfr * 1032 + quad * 8;
            f4 accm = {0.f, 0.f, 0.f, 0.f};
#pragma unroll 4
            for (int ks = 0; ks < 32; ++ks) {
                h8 a = *(const h8*)(ar + ks * 32);
                accm = __builtin_amdgcn_mfma_f32_16x16x32_f16(a, *(const h8*)(pw + ks * 32 + quad * 8), accm, 0, 0, 0);
            }
            if (meld) {
#pragma unroll
                for (int r = 0; r < 4; ++r) {
                    int b = bh * 16 + quad * 4 + r;
                    float v = accm[r] + biasP;
                    if (799 > s_len[b]) v = 0.f;
                    out[(size_t)b * (TMEL * MM) + (size_t)799 * MM + j * 16 + lo] = v;
                }
            } else if (lo == 0) {
#pragma unroll
                for (int r = 0; r < 4; ++r) {
                    int b = bh * 16 + quad * 4 + r;
                    float v = accm[r] + biasP;
                    if (799 > s_len[b]) v = 1000.f;
                    out[GATE_OFF + (size_t)b * TMEL + 799] = v;
                }
            }
        }
    }
}

// ---------------------------------------------------------------------------

extern "C" void kernel_launch(void* const* d_in, const int* in_sizes, int n_in,
                              void* d_out, int out_size, void* d_ws, size_t ws_size,
                              hipStream_t stream) {
    const int* x = (const int*)d_in[0];
    const int* tlens = (const int*)d_in[1];
    const int* mlens = (const int*)d_in[3];
    const float* emb = (const float*)d_in[4];
    const float* c1w = (const float*)d_in[5];
    const float* c1b = (const float*)d_in[6];
    const float* bn1g = (const float*)d_in[7];
    const float* bn1b = (const float*)d_in[8];
    const float* c2w = (const float*)d_in[9];
    const float* c2b = (const float*)d_in[10];
    const float* bn2g = (const float*)d_in[11];
    const float* bn2b = (const float*)d_in[12];
    const float* wihf = (const float*)d_in[13];
    const float* whhf = (const float*)d_in[14];
    const float* bihf = (const float*)d_in[15];
    const float* bhhf = (const float*)d_in[16];
    const float* wihb = (const float*)d_in[17];
    const float* whhb = (const float*)d_in[18];
    const float* bihb = (const float*)d_in[19];
    const float* bhhb = (const float*)d_in[20];
    const float* dwih = (const float*)d_in[21];
    const float* dwhh = (const float*)d_in[22];
    const float* dbih = (const float*)d_in[23];
    const float* dbhh = (const float*)d_in[24];
    const float* projw = (const float*)d_in[25];
    const float* projb = (const float*)d_in[26];
    const float* gatew = (const float*)d_in[27];
    const float* gateb = (const float*)d_in[28];
    float* out = (float*)d_out;
    char* ws = (char*)d_ws;

    unsigned* bars = (unsigned*)(ws + WS_BARS);              // encF @0, encB @+8KB, dec @+16KB
    unsigned* bar_dec = (unsigned*)(ws + WS_BARS + 16384);
    half_t* henc = (half_t*)(ws + WS_HENC);
    half_t* hd = (half_t*)(ws + WS_HD);
    half_t* bufX = (half_t*)(ws + WS_BUFX);
    half_t* bufY = (half_t*)(ws + WS_BUFY);
    float* convf = (float*)(ws + WS_CONVF);
    half_t* weff = (half_t*)(ws + WS_WEFF);
    half_t* w0 = (half_t*)(ws + WS_W0);
    half_t* wp1 = (half_t*)(ws + WS_WP1);
    half_t* wp2 = (half_t*)(ws + WS_WP2);
    float* meanb = (float*)(ws + WS_MEAN);
    float* rstdb = (float*)(ws + WS_RSTD);
    half_t* wihp = (half_t*)(ws + WS_WIHP);
    half_t* whhp = (half_t*)(ws + WS_WHHP);
    float* bsum = (float*)(ws + WS_BSUM);
    float* beff = (float*)(ws + WS_BEFF);
    float* b0 = (float*)(ws + WS_B0);
    half_t* projwb = (half_t*)(ws + WS_PROJW);
    half_t* projg = (half_t*)(ws + WS_PROJG);
    float* cel = (float*)(ws + WS_CEL);

    // zero barrier state + encoder ring slot 0
    hipMemsetAsync(d_ws, 0, (size_t)WS_ZERO_BYTES, stream);

    // front-end
    k_embed<<<NROWS, 256, 0, stream>>>(x, emb, bufX);
    k_packconvw<<<(3 * EE * EE + 255) / 256, 256, 0, stream>>>(c1w, wp1);
    k_conv<<<dim3(128, 32), 256, 0, stream>>>(bufX, wp1, c1b, convf);
    k_bnstats<<<EE, 256, 0, stream>>>(convf, meanb, rstdb);
    k_bnapply<<<(NROWS * EE) / 256, 256, 0, stream>>>(convf, meanb, rstdb, bn1g, bn1b, bufY);
    k_packconvw<<<(3 * EE * EE + 255) / 256, 256, 0, stream>>>(c2w, wp2);
    k_conv<<<dim3(128, 32), 256, 0, stream>>>(bufY, wp2, c2b, convf);
    k_bnstats<<<EE, 256, 0, stream>>>(convf, meanb, rstdb);
    k_bnapply<<<(NROWS * EE) / 256, 256, 0, stream>>>(convf, meanb, rstdb, bn2g, bn2b, bufX);

    // encoder weight prep
    const int encTot = 2048 * 512;
    k_packrec<<<(encTot + 255) / 256, 256, 0, stream>>>(wihf, wihp, HH, 9, encTot);
    k_packrec<<<(encTot + 255) / 256, 256, 0, stream>>>(wihb, wihp + encTot, HH, 9, encTot);
    k_packrec<<<(encTot + 255) / 256, 256, 0, stream>>>(whhf, whhp, HH, 9, encTot);
    k_packrec<<<(encTot + 255) / 256, 256, 0, stream>>>(whhb, whhp + encTot, HH, 9, encTot);
    k_bsumenc<<<16, 256, 0, stream>>>(bihf, bhhf, bihb, bhhb, bsum);

    // persistent bidirectional encoder (writes hd ring slot 0 + cel)
    k_enc<<<64, 512, 0, stream>>>(bufX, wihp, whhp, bsum, tlens, henc, hd, cel, bars);

    // decoder weight prep (into retired convf region)
    k_weff<<<dim3(4096, 4), 256, 0, stream>>>(dwhh, dwih, projw, weff, w0);
    k_bdec<<<16, 256, 0, stream>>>(dbih, dbhh, dwih, projb, beff, b0);
    k_cast<<<(MM * DD + 255) / 256, 256, 0, stream>>>(projw, projwb, MM * DD);
    k_projg<<<(16 * DD + 255) / 256, 256, 0, stream>>>(gatew, projg);

    // persistent decoder
    k_dec<<<64, 512, 0, stream>>>(weff, w0, beff, b0, projwb, projg, projb, gateb,
                                  mlens, cel, hd, out, bar_dec);

    // mask output
    k_mask<<<(B_ * TMEL + 255) / 256, 256, 0, stream>>>(mlens, out);

    (void)in_sizes; (void)n_in; (void)out_size; (void)ws_size;
}